// Round 6
// baseline (1211.229 us; speedup 1.0000x reference)
//
#include <hip/hip_runtime.h>
#include <hip/hip_bf16.h>

#define N_NODES 50000
#define N_EDGES 800000
#define NUM_MOL 2000

typedef __attribute__((ext_vector_type(8))) short short8;
typedef __attribute__((ext_vector_type(4))) float f32x4;

union bfbits { __hip_bfloat16 b; short s; };

// ---------------------------------------------------------------------------
// Type tables:
//   T1[t,c]  = atom_table[t,:] @ Wi[0:128,c]            (119x128)
//   T2c[a,c] = bond_table[a,:] @ Wi[128:192,c] + bi[c]  (4x128)
//   U1[t,c]  = atom_table[t,:] @ Wu1[0:128,c]           (119x128)
//   U2c[a,c] = bond_table[a,:] @ Wu1[128:192,c] + bu1[c](4x128)
// ---------------------------------------------------------------------------
__global__ void k_tables(const float* __restrict__ atom_table,
                         const float* __restrict__ bond_table,
                         const float* __restrict__ Wi,
                         const float* __restrict__ bi,
                         const float* __restrict__ Wu1,
                         const float* __restrict__ bu1,
                         float* __restrict__ T1, float* __restrict__ U1,
                         float* __restrict__ T2c, float* __restrict__ U2c) {
  int b = blockIdx.x;
  int c = threadIdx.x;
  if (b < 119) {
    float t = 0.f, u = 0.f;
    for (int k = 0; k < 128; k++) {
      float a = atom_table[b * 128 + k];
      t += a * Wi[k * 128 + c];
      u += a * Wu1[k * 128 + c];
    }
    T1[b * 128 + c] = t;
    U1[b * 128 + c] = u;
  } else {
    int a = b - 119;
    float t = bi[c], u = bu1[c];
    for (int k = 0; k < 64; k++) {
      float bv = bond_table[a * 64 + k];
      t += bv * Wi[(128 + k) * 128 + c];
      u += bv * Wu1[(128 + k) * 128 + c];
    }
    T2c[a * 128 + c] = t;
    U2c[a * 128 + c] = u;
  }
}

// TT[x*4+a, c] = relu(T1[x,c] + T2c[a,c])
__global__ void k_tt(const float* __restrict__ T1, const float* __restrict__ T2c,
                     float* __restrict__ TT) {
  int r = blockIdx.x;   // 0..475
  int c = threadIdx.x;
  float v = T1[(r >> 2) * 128 + c] + T2c[(r & 3) * 128 + c];
  TT[r * 128 + c] = v > 0.f ? v : 0.f;
}

// Wt[n][k]  = bf16(Wu2[k][n])           (hi part, transposed for B-frags)
// Wlo[n][k] = bf16(Wu2[k][n] - fp32(Wt)) (lo residual)
__global__ void k_wt(const float* __restrict__ Wu2, short* __restrict__ Wt,
                     short* __restrict__ Wlo) {
  int n = blockIdx.x;
  int k = threadIdx.x;
  float w = Wu2[k * 128 + n];
  bfbits hi; hi.b = __float2bfloat16(w);
  float hf = __bfloat162float(hi.b);
  bfbits lo; lo.b = __float2bfloat16(w - hf);
  Wt[n * 128 + k] = hi.s;
  Wlo[n * 128 + k] = lo.s;
}

// ---------------------------------------------------------------------------
// CSR build: histogram of dst, single-block scan, fill.
// ---------------------------------------------------------------------------
__global__ void k_hist(const int* __restrict__ eidx, int* __restrict__ cnt) {
  int e = blockIdx.x * 256 + threadIdx.x;
  atomicAdd(&cnt[eidx[N_EDGES + e]], 1);
}

__global__ __launch_bounds__(1024) void k_scan(const int* __restrict__ cnt,
                                               int* __restrict__ rowptr,
                                               int* __restrict__ cursor) {
  __shared__ int buf[1024];
  __shared__ int carry_s;
  int t = threadIdx.x;
  if (t == 0) carry_s = 0;
  __syncthreads();
  for (int base = 0; base < N_NODES; base += 1024) {
    int i = base + t;
    int v = (i < N_NODES) ? cnt[i] : 0;
    buf[t] = v;
    __syncthreads();
    for (int off = 1; off < 1024; off <<= 1) {
      int add = (t >= off) ? buf[t - off] : 0;
      __syncthreads();
      buf[t] += add;
      __syncthreads();
    }
    int carry = carry_s;
    if (i < N_NODES) {
      rowptr[i + 1] = carry + buf[t];
      cursor[i] = carry + buf[t] - v;   // exclusive prefix
    }
    __syncthreads();
    if (t == 1023) carry_s = carry + buf[1023];
    __syncthreads();
  }
  if (t == 0) rowptr[0] = 0;
}

__global__ void k_fill(const int* __restrict__ eidx, const int* __restrict__ attr,
                       int* __restrict__ cursor, int* __restrict__ csr) {
  int e = blockIdx.x * 256 + threadIdx.x;
  int d = eidx[N_EDGES + e];
  int pos = atomicAdd(&cursor[d], 1);
  csr[pos] = eidx[e] * 4 + attr[e];
}

// ---------------------------------------------------------------------------
// Gather initial messages: A[n] = sum_{edges into n} TT[x[src]*4+attr]  (fp32)
// ---------------------------------------------------------------------------
__global__ void k_gather0(const int* __restrict__ rowptr, const int* __restrict__ csr,
                          const int* __restrict__ x, const float* __restrict__ TT,
                          float* __restrict__ A_) {
  int n = blockIdx.x * 4 + (threadIdx.x >> 6);
  int lane = threadIdx.x & 63;
  int beg = rowptr[n], end = rowptr[n + 1];
  float ax = 0.f, ay = 0.f;
  int i = beg;
  for (; i + 1 < end; i += 2) {
    int m0 = csr[i], m1 = csr[i + 1];
    int t0 = x[m0 >> 2] * 4 + (m0 & 3);
    int t1 = x[m1 >> 2] * 4 + (m1 & 3);
    float2 v0 = *(const float2*)&TT[t0 * 128 + lane * 2];
    float2 v1 = *(const float2*)&TT[t1 * 128 + lane * 2];
    ax += v0.x + v1.x;
    ay += v0.y + v1.y;
  }
  if (i < end) {
    int m0 = csr[i];
    int t0 = x[m0 >> 2] * 4 + (m0 & 3);
    float2 v0 = *(const float2*)&TT[t0 * 128 + lane * 2];
    ax += v0.x;
    ay += v0.y;
  }
  float2 o; o.x = ax; o.y = ay;
  *(float2*)&A_[n * 128 + lane * 2] = o;
}

// ---------------------------------------------------------------------------
// Gather messages: A[n] = sum_{edges into n} M_bf16[src*4+attr]
// ---------------------------------------------------------------------------
__global__ void k_gather(const int* __restrict__ rowptr, const int* __restrict__ csr,
                         const __hip_bfloat16* __restrict__ M, float* __restrict__ A_) {
  int n = blockIdx.x * 4 + (threadIdx.x >> 6);
  int lane = threadIdx.x & 63;
  int beg = rowptr[n], end = rowptr[n + 1];
  float ax = 0.f, ay = 0.f;
  int i = beg;
  for (; i + 1 < end; i += 2) {
    int m0 = csr[i], m1 = csr[i + 1];
    float2 v0 = __bfloat1622float2(*(const __hip_bfloat162*)&M[m0 * 128 + lane * 2]);
    float2 v1 = __bfloat1622float2(*(const __hip_bfloat162*)&M[m1 * 128 + lane * 2]);
    ax += v0.x + v1.x;
    ay += v0.y + v1.y;
  }
  if (i < end) {
    int m0 = csr[i];
    float2 v0 = __bfloat1622float2(*(const __hip_bfloat162*)&M[m0 * 128 + lane * 2]);
    ax += v0.x;
    ay += v0.y;
  }
  float2 o; o.x = ax; o.y = ay;
  *(float2*)&A_[n * 128 + lane * 2] = o;
}

// ---------------------------------------------------------------------------
// k_mm1: B = A @ Wu1[192:320,:]  fp32 tiled GEMM (kept fp32 for accuracy).
// ---------------------------------------------------------------------------
__global__ __launch_bounds__(256, 4) void k_mm1(const float* __restrict__ A_,
                                                const float* __restrict__ Wu1,
                                                float* __restrict__ B_) {
  __shared__ float Hs[64][132];
  int t = threadIdx.x;
  int base = blockIdx.x * 64;
#pragma unroll
  for (int j = 0; j < 8; j++) {
    int idx = j * 256 + t;        // 0..2047 float4 slots
    int rr = idx >> 5;            // local row
    int kq = idx & 31;            // float4 index in k
    int n = base + rr;
    if (n >= N_NODES) n = N_NODES - 1;
    float4 v = *(const float4*)&A_[n * 128 + kq * 4];
    *(float4*)&Hs[rr][kq * 4] = v;
  }
  __syncthreads();
  int r0 = (t >> 4) * 4;
  int c0 = (t & 15) * 8;
  const float* W = Wu1 + 192 * 128;
  float acc[4][8];
#pragma unroll
  for (int r = 0; r < 4; r++)
#pragma unroll
    for (int j = 0; j < 8; j++) acc[r][j] = 0.f;
#pragma unroll 2
  for (int kq = 0; kq < 32; kq++) {
    const int k = kq * 4;
    float h0[4], h1[4], h2[4], h3[4];
    *(float4*)h0 = *(const float4*)&Hs[r0][k];
    *(float4*)h1 = *(const float4*)&Hs[r0 + 1][k];
    *(float4*)h2 = *(const float4*)&Hs[r0 + 2][k];
    *(float4*)h3 = *(const float4*)&Hs[r0 + 3][k];
#pragma unroll
    for (int i = 0; i < 4; i++) {
      float w[8];
      *(float4*)&w[0] = *(const float4*)&W[(k + i) * 128 + c0];
      *(float4*)&w[4] = *(const float4*)&W[(k + i) * 128 + c0 + 4];
      float hv[4] = {h0[i], h1[i], h2[i], h3[i]};
#pragma unroll
      for (int r = 0; r < 4; r++)
#pragma unroll
        for (int j = 0; j < 8; j++) acc[r][j] += hv[r] * w[j];
    }
  }
#pragma unroll
  for (int r = 0; r < 4; r++) {
    int n = base + r0 + r;
    if (n < N_NODES) {
      float4 o0, o1;
      o0.x = acc[r][0]; o0.y = acc[r][1]; o0.z = acc[r][2]; o0.w = acc[r][3];
      o1.x = acc[r][4]; o1.y = acc[r][5]; o1.z = acc[r][6]; o1.w = acc[r][7];
      *(float4*)&B_[n * 128 + c0] = o0;
      *(float4*)&B_[n * 128 + c0 + 4] = o1;
    }
  }
}

// ---------------------------------------------------------------------------
// k_mm2 (MFMA, hi/lo split on BOTH operands): slab of 16 H rows per wave.
//   H = relu(U1[x]+B+U2c) built in A-frag layout, split ahi+alo (bf16 pair).
//   W split Whi (preloaded, 128 VGPRs) + Wlo (streamed per kc).
//   D = ahi@Whi + alo@Whi + ahi@Wlo  (alo@Wlo ~2^-18, dropped).
// ---------------------------------------------------------------------------
__global__ __launch_bounds__(256, 2) void k_mm2(const float* __restrict__ B_,
                                                const int* __restrict__ x,
                                                const float* __restrict__ U1,
                                                const float* __restrict__ U2c,
                                                const short* __restrict__ Wt,
                                                const short* __restrict__ Wlo,
                                                const float* __restrict__ bu2,
                                                __hip_bfloat16* __restrict__ M) {
  int t = threadIdx.x;
  int lane = t & 63;
  int m = lane & 15;
  int quad = lane >> 4;
  int s = blockIdx.x * 4 + (t >> 6);   // slab 0..12499

  // preload all 32 hi B-fragments (kc 0..3, nt 0..7): 128 VGPRs
  short8 bf[4][8];
#pragma unroll
  for (int kc = 0; kc < 4; kc++)
#pragma unroll
    for (int nt = 0; nt < 8; nt++)
      bf[kc][nt] = *(const short8*)&Wt[(nt * 16 + m) * 128 + kc * 32 + quad * 8];

  int rbase = s * 16;
  int node = s * 4 + (m >> 2);
  int attr = m & 3;
  int xn = x[node];

  f32x4 acc[8];
#pragma unroll
  for (int nt = 0; nt < 8; nt++) acc[nt] = (f32x4){0.f, 0.f, 0.f, 0.f};

#pragma unroll
  for (int kc = 0; kc < 4; kc++) {
    int k0 = kc * 32 + quad * 8;
    short8 ahi, alo;
    {
      float u1a[8], bba[8], u2a[8];
      *(float4*)&u1a[0] = *(const float4*)&U1[xn * 128 + k0];
      *(float4*)&u1a[4] = *(const float4*)&U1[xn * 128 + k0 + 4];
      *(float4*)&bba[0] = *(const float4*)&B_[node * 128 + k0];
      *(float4*)&bba[4] = *(const float4*)&B_[node * 128 + k0 + 4];
      *(float4*)&u2a[0] = *(const float4*)&U2c[attr * 128 + k0];
      *(float4*)&u2a[4] = *(const float4*)&U2c[attr * 128 + k0 + 4];
#pragma unroll
      for (int j = 0; j < 8; j++) {
        float h = u1a[j] + bba[j] + u2a[j];
        h = h > 0.f ? h : 0.f;
        bfbits hi; hi.b = __float2bfloat16(h);
        float hf = __bfloat162float(hi.b);
        bfbits lo; lo.b = __float2bfloat16(h - hf);
        ahi[j] = hi.s;
        alo[j] = lo.s;
      }
    }
    // stream lo weight frags for this kc
    short8 lf[8];
#pragma unroll
    for (int nt = 0; nt < 8; nt++)
      lf[nt] = *(const short8*)&Wlo[(nt * 16 + m) * 128 + kc * 32 + quad * 8];
#pragma unroll
    for (int nt = 0; nt < 8; nt++) {
      acc[nt] = __builtin_amdgcn_mfma_f32_16x16x32_bf16(ahi, bf[kc][nt], acc[nt], 0, 0, 0);
      acc[nt] = __builtin_amdgcn_mfma_f32_16x16x32_bf16(alo, bf[kc][nt], acc[nt], 0, 0, 0);
      acc[nt] = __builtin_amdgcn_mfma_f32_16x16x32_bf16(ahi, lf[nt], acc[nt], 0, 0, 0);
    }
  }

  // epilogue: D[row=quad*4+r][col=lane&15] ; row -> slab row, col -> channel
#pragma unroll
  for (int nt = 0; nt < 8; nt++) {
    float bias = bu2[nt * 16 + m];
#pragma unroll
    for (int r = 0; r < 4; r++) {
      float v = acc[nt][r] + bias;
      v = v > 0.f ? v : 0.f;
      M[(rbase + quad * 4 + r) * 128 + nt * 16 + m] = __float2bfloat16(v);
    }
  }
}

// ---------------------------------------------------------------------------
// mol_state[batch[n]] += node_state[n]
// ---------------------------------------------------------------------------
__global__ void k_mol(const float* __restrict__ node,
                      const int* __restrict__ batch,
                      float* __restrict__ mol) {
  int idx = blockIdx.x * 256 + threadIdx.x;
  int n = idx >> 7;
  int c = idx & 127;
  atomicAdd(&mol[batch[n] * 128 + c], node[idx]);
}

// ---------------------------------------------------------------------------
// out[m] = relu(mol[m] @ Wr1 + br1) @ Wr2 + br2
// ---------------------------------------------------------------------------
__global__ __launch_bounds__(256) void k_readout(const float* __restrict__ mol,
                                                 const float* __restrict__ Wr1,
                                                 const float* __restrict__ br1,
                                                 const float* __restrict__ Wr2,
                                                 const float* __restrict__ br2,
                                                 float* __restrict__ out) {
  int m = blockIdx.x;
  __shared__ float ms[128];
  __shared__ float red[256];
  int t = threadIdx.x;
  if (t < 128) ms[t] = mol[m * 128 + t];
  __syncthreads();
  float part = 0.f;
#pragma unroll
  for (int jj = 0; jj < 2; jj++) {
    int j = t + jj * 256;
    float acc = br1[j];
#pragma unroll
    for (int k = 0; k < 128; k += 4) {
      float4 m4 = *(const float4*)&ms[k];
      acc += m4.x * Wr1[k * 512 + j] + m4.y * Wr1[(k + 1) * 512 + j] +
             m4.z * Wr1[(k + 2) * 512 + j] + m4.w * Wr1[(k + 3) * 512 + j];
    }
    acc = acc > 0.f ? acc : 0.f;
    part += acc * Wr2[j];
  }
  red[t] = part;
  __syncthreads();
  for (int s = 128; s > 0; s >>= 1) {
    if (t < s) red[t] += red[t + s];
    __syncthreads();
  }
  if (t == 0) out[m] = red[0] + br2[0];
}

// ---------------------------------------------------------------------------
extern "C" void kernel_launch(void* const* d_in, const int* in_sizes, int n_in,
                              void* d_out, int out_size, void* d_ws, size_t ws_size,
                              hipStream_t stream) {
  const int* x        = (const int*)d_in[0];
  const int* eattr    = (const int*)d_in[1];
  const int* eidx     = (const int*)d_in[2];
  const int* batch    = (const int*)d_in[3];
  const float* atom_table = (const float*)d_in[4];
  const float* bond_table = (const float*)d_in[5];
  const float* Wi  = (const float*)d_in[6];
  const float* bi  = (const float*)d_in[7];
  const float* Wu1 = (const float*)d_in[8];
  const float* bu1 = (const float*)d_in[9];
  const float* Wu2 = (const float*)d_in[10];
  const float* bu2 = (const float*)d_in[11];
  const float* Wr1 = (const float*)d_in[12];
  const float* br1 = (const float*)d_in[13];
  const float* Wr2 = (const float*)d_in[14];
  const float* br2 = (const float*)d_in[15];
  float* out = (float*)d_out;

  char* ws = (char*)d_ws;
  __hip_bfloat16* M = (__hip_bfloat16*)(ws);       //  51,200,000 B (bf16)
  short* Wt     = (short*)(ws + 51200000);         //      32,768 B (bf16 Wu2^T hi)
  short* Wlo    = (short*)(ws + 51232768);         //      32,768 B (bf16 Wu2^T lo)
  float* A      = (float*)(ws + 102400000);        //  25,600,000 B
  float* B      = (float*)(ws + 128000000);        //  25,600,000 B
  int*   csr    = (int*)  (ws + 153600000);        //   3,200,000 B
  int*   rowptr = (int*)  (ws + 156800000);        //     200,064 B
  float* T1     = (float*)(ws + 157000064);        //      60,928 B
  float* U1     = (float*)(ws + 157060992);        //      60,928 B
  float* T2c    = (float*)(ws + 157121920);        //       2,048 B
  float* U2c    = (float*)(ws + 157123968);        //       2,048 B
  float* TT     = (float*)(ws + 157126016);        //     243,712 B
  float* mol    = (float*)(ws + 157369728);        //   1,024,000 B
  // cnt/cursor alias B: only live before the first k_mm1 write to B.
  int*   cnt    = (int*)B;
  int*   cursor = (int*)(ws + 128000000 + 204800);

  hipMemsetAsync(cnt, 0, N_NODES * sizeof(int), stream);
  k_tables<<<123, 128, 0, stream>>>(atom_table, bond_table, Wi, bi, Wu1, bu1,
                                    T1, U1, T2c, U2c);
  k_tt<<<476, 128, 0, stream>>>(T1, T2c, TT);
  k_wt<<<128, 128, 0, stream>>>(Wu2, Wt, Wlo);
  k_hist<<<N_EDGES / 256, 256, 0, stream>>>(eidx, cnt);
  k_scan<<<1, 1024, 0, stream>>>(cnt, rowptr, cursor);
  k_fill<<<N_EDGES / 256, 256, 0, stream>>>(eidx, eattr, cursor, csr);

  k_gather0<<<N_NODES / 4, 256, 0, stream>>>(rowptr, csr, x, TT, A);

  for (int p = 0; p < 4; p++) {
    k_mm1<<<(N_NODES + 63) / 64, 256, 0, stream>>>(A, Wu1, B);
    k_mm2<<<(4 * N_NODES) / 64, 256, 0, stream>>>(B, x, U1, U2c, Wt, Wlo, bu2, M);
    k_gather<<<N_NODES / 4, 256, 0, stream>>>(rowptr, csr, M, A);
  }

  hipMemsetAsync(mol, 0, NUM_MOL * 128 * sizeof(float), stream);
  k_mol<<<(N_NODES * 128) / 256, 256, 0, stream>>>(A, batch, mol);
  k_readout<<<NUM_MOL, 256, 0, stream>>>(mol, Wr1, br1, Wr2, br2, out);
}

// Round 7
// 1133.874 us; speedup vs baseline: 1.0682x; 1.0682x over previous
//
#include <hip/hip_runtime.h>
#include <hip/hip_bf16.h>

#define N_NODES 50000
#define N_EDGES 800000
#define NUM_MOL 2000

typedef __attribute__((ext_vector_type(8))) short short8;
typedef __attribute__((ext_vector_type(4))) float f32x4;

union bfbits { __hip_bfloat16 b; short s; };

// ---------------------------------------------------------------------------
// Type tables:
//   T1[t,c]  = atom_table[t,:] @ Wi[0:128,c]            (119x128)
//   T2c[a,c] = bond_table[a,:] @ Wi[128:192,c] + bi[c]  (4x128)
//   U1[t,c]  = atom_table[t,:] @ Wu1[0:128,c]           (119x128)
//   U2c[a,c] = bond_table[a,:] @ Wu1[128:192,c] + bu1[c](4x128)
// ---------------------------------------------------------------------------
__global__ void k_tables(const float* __restrict__ atom_table,
                         const float* __restrict__ bond_table,
                         const float* __restrict__ Wi,
                         const float* __restrict__ bi,
                         const float* __restrict__ Wu1,
                         const float* __restrict__ bu1,
                         float* __restrict__ T1, float* __restrict__ U1,
                         float* __restrict__ T2c, float* __restrict__ U2c) {
  int b = blockIdx.x;
  int c = threadIdx.x;
  if (b < 119) {
    float t = 0.f, u = 0.f;
    for (int k = 0; k < 128; k++) {
      float a = atom_table[b * 128 + k];
      t += a * Wi[k * 128 + c];
      u += a * Wu1[k * 128 + c];
    }
    T1[b * 128 + c] = t;
    U1[b * 128 + c] = u;
  } else {
    int a = b - 119;
    float t = bi[c], u = bu1[c];
    for (int k = 0; k < 64; k++) {
      float bv = bond_table[a * 64 + k];
      t += bv * Wi[(128 + k) * 128 + c];
      u += bv * Wu1[(128 + k) * 128 + c];
    }
    T2c[a * 128 + c] = t;
    U2c[a * 128 + c] = u;
  }
}

// TT[x*4+a, c] = relu(T1[x,c] + T2c[a,c])
__global__ void k_tt(const float* __restrict__ T1, const float* __restrict__ T2c,
                     float* __restrict__ TT) {
  int r = blockIdx.x;   // 0..475
  int c = threadIdx.x;
  float v = T1[(r >> 2) * 128 + c] + T2c[(r & 3) * 128 + c];
  TT[r * 128 + c] = v > 0.f ? v : 0.f;
}

// Wt[n][k]  = bf16(Wu2[k][n])            (hi, transposed for B-frags)
// Wlo[n][k] = bf16(Wu2[k][n] - fp32(Wt)) (lo residual)
__global__ void k_wt(const float* __restrict__ Wu2, short* __restrict__ Wt,
                     short* __restrict__ Wlo) {
  int n = blockIdx.x;
  int k = threadIdx.x;
  float w = Wu2[k * 128 + n];
  bfbits hi; hi.b = __float2bfloat16(w);
  float hf = __bfloat162float(hi.b);
  bfbits lo; lo.b = __float2bfloat16(w - hf);
  Wt[n * 128 + k] = hi.s;
  Wlo[n * 128 + k] = lo.s;
}

// ---------------------------------------------------------------------------
// CSR build: histogram of dst, single-block scan, fill.
// ---------------------------------------------------------------------------
__global__ void k_hist(const int* __restrict__ eidx, int* __restrict__ cnt) {
  int e = blockIdx.x * 256 + threadIdx.x;
  atomicAdd(&cnt[eidx[N_EDGES + e]], 1);
}

__global__ __launch_bounds__(1024) void k_scan(const int* __restrict__ cnt,
                                               int* __restrict__ rowptr,
                                               int* __restrict__ cursor) {
  __shared__ int buf[1024];
  __shared__ int carry_s;
  int t = threadIdx.x;
  if (t == 0) carry_s = 0;
  __syncthreads();
  for (int base = 0; base < N_NODES; base += 1024) {
    int i = base + t;
    int v = (i < N_NODES) ? cnt[i] : 0;
    buf[t] = v;
    __syncthreads();
    for (int off = 1; off < 1024; off <<= 1) {
      int add = (t >= off) ? buf[t - off] : 0;
      __syncthreads();
      buf[t] += add;
      __syncthreads();
    }
    int carry = carry_s;
    if (i < N_NODES) {
      rowptr[i + 1] = carry + buf[t];
      cursor[i] = carry + buf[t] - v;   // exclusive prefix
    }
    __syncthreads();
    if (t == 1023) carry_s = carry + buf[1023];
    __syncthreads();
  }
  if (t == 0) rowptr[0] = 0;
}

__global__ void k_fill(const int* __restrict__ eidx, const int* __restrict__ attr,
                       int* __restrict__ cursor, int* __restrict__ csr) {
  int e = blockIdx.x * 256 + threadIdx.x;
  int d = eidx[N_EDGES + e];
  int pos = atomicAdd(&cursor[d], 1);
  csr[pos] = eidx[e] * 4 + attr[e];
}

// ---------------------------------------------------------------------------
// Gather initial messages: A[n] = sum_{edges into n} TT[x[src]*4+attr]  (fp32)
// 4-deep unroll for MLP.
// ---------------------------------------------------------------------------
__global__ void k_gather0(const int* __restrict__ rowptr, const int* __restrict__ csr,
                          const int* __restrict__ x, const float* __restrict__ TT,
                          float* __restrict__ A_) {
  int n = blockIdx.x * 4 + (threadIdx.x >> 6);
  int lane = threadIdx.x & 63;
  int beg = rowptr[n], end = rowptr[n + 1];
  float ax = 0.f, ay = 0.f;
  int i = beg;
  for (; i + 3 < end; i += 4) {
    int m0 = csr[i], m1 = csr[i + 1], m2 = csr[i + 2], m3 = csr[i + 3];
    int t0 = x[m0 >> 2] * 4 + (m0 & 3);
    int t1 = x[m1 >> 2] * 4 + (m1 & 3);
    int t2 = x[m2 >> 2] * 4 + (m2 & 3);
    int t3 = x[m3 >> 2] * 4 + (m3 & 3);
    float2 v0 = *(const float2*)&TT[t0 * 128 + lane * 2];
    float2 v1 = *(const float2*)&TT[t1 * 128 + lane * 2];
    float2 v2 = *(const float2*)&TT[t2 * 128 + lane * 2];
    float2 v3 = *(const float2*)&TT[t3 * 128 + lane * 2];
    ax += (v0.x + v1.x) + (v2.x + v3.x);
    ay += (v0.y + v1.y) + (v2.y + v3.y);
  }
  for (; i < end; i++) {
    int m0 = csr[i];
    int t0 = x[m0 >> 2] * 4 + (m0 & 3);
    float2 v0 = *(const float2*)&TT[t0 * 128 + lane * 2];
    ax += v0.x;
    ay += v0.y;
  }
  float2 o; o.x = ax; o.y = ay;
  *(float2*)&A_[n * 128 + lane * 2] = o;
}

// ---------------------------------------------------------------------------
// Gather messages: A[n] = sum_{edges into n} M_bf16[src*4+attr], 4-deep unroll.
// ---------------------------------------------------------------------------
__global__ void k_gather(const int* __restrict__ rowptr, const int* __restrict__ csr,
                         const __hip_bfloat16* __restrict__ M, float* __restrict__ A_) {
  int n = blockIdx.x * 4 + (threadIdx.x >> 6);
  int lane = threadIdx.x & 63;
  int beg = rowptr[n], end = rowptr[n + 1];
  float ax = 0.f, ay = 0.f;
  int i = beg;
  for (; i + 3 < end; i += 4) {
    int m0 = csr[i], m1 = csr[i + 1], m2 = csr[i + 2], m3 = csr[i + 3];
    float2 v0 = __bfloat1622float2(*(const __hip_bfloat162*)&M[m0 * 128 + lane * 2]);
    float2 v1 = __bfloat1622float2(*(const __hip_bfloat162*)&M[m1 * 128 + lane * 2]);
    float2 v2 = __bfloat1622float2(*(const __hip_bfloat162*)&M[m2 * 128 + lane * 2]);
    float2 v3 = __bfloat1622float2(*(const __hip_bfloat162*)&M[m3 * 128 + lane * 2]);
    ax += (v0.x + v1.x) + (v2.x + v3.x);
    ay += (v0.y + v1.y) + (v2.y + v3.y);
  }
  for (; i < end; i++) {
    int m0 = csr[i];
    float2 v0 = __bfloat1622float2(*(const __hip_bfloat162*)&M[m0 * 128 + lane * 2]);
    ax += v0.x;
    ay += v0.y;
  }
  float2 o; o.x = ax; o.y = ay;
  *(float2*)&A_[n * 128 + lane * 2] = o;
}

// ---------------------------------------------------------------------------
// k_mm1: B = A @ Wu1[192:320,:]  fp32 tiled GEMM (kept fp32 for accuracy).
// ---------------------------------------------------------------------------
__global__ __launch_bounds__(256, 4) void k_mm1(const float* __restrict__ A_,
                                                const float* __restrict__ Wu1,
                                                float* __restrict__ B_) {
  __shared__ float Hs[64][132];
  int t = threadIdx.x;
  int base = blockIdx.x * 64;
#pragma unroll
  for (int j = 0; j < 8; j++) {
    int idx = j * 256 + t;        // 0..2047 float4 slots
    int rr = idx >> 5;            // local row
    int kq = idx & 31;            // float4 index in k
    int n = base + rr;
    if (n >= N_NODES) n = N_NODES - 1;
    float4 v = *(const float4*)&A_[n * 128 + kq * 4];
    *(float4*)&Hs[rr][kq * 4] = v;
  }
  __syncthreads();
  int r0 = (t >> 4) * 4;
  int c0 = (t & 15) * 8;
  const float* W = Wu1 + 192 * 128;
  float acc[4][8];
#pragma unroll
  for (int r = 0; r < 4; r++)
#pragma unroll
    for (int j = 0; j < 8; j++) acc[r][j] = 0.f;
#pragma unroll 2
  for (int kq = 0; kq < 32; kq++) {
    const int k = kq * 4;
    float h0[4], h1[4], h2[4], h3[4];
    *(float4*)h0 = *(const float4*)&Hs[r0][k];
    *(float4*)h1 = *(const float4*)&Hs[r0 + 1][k];
    *(float4*)h2 = *(const float4*)&Hs[r0 + 2][k];
    *(float4*)h3 = *(const float4*)&Hs[r0 + 3][k];
#pragma unroll
    for (int i = 0; i < 4; i++) {
      float w[8];
      *(float4*)&w[0] = *(const float4*)&W[(k + i) * 128 + c0];
      *(float4*)&w[4] = *(const float4*)&W[(k + i) * 128 + c0 + 4];
      float hv[4] = {h0[i], h1[i], h2[i], h3[i]};
#pragma unroll
      for (int r = 0; r < 4; r++)
#pragma unroll
        for (int j = 0; j < 8; j++) acc[r][j] += hv[r] * w[j];
    }
  }
#pragma unroll
  for (int r = 0; r < 4; r++) {
    int n = base + r0 + r;
    if (n < N_NODES) {
      float4 o0, o1;
      o0.x = acc[r][0]; o0.y = acc[r][1]; o0.z = acc[r][2]; o0.w = acc[r][3];
      o1.x = acc[r][4]; o1.y = acc[r][5]; o1.z = acc[r][6]; o1.w = acc[r][7];
      *(float4*)&B_[n * 128 + c0] = o0;
      *(float4*)&B_[n * 128 + c0 + 4] = o1;
    }
  }
}

// ---------------------------------------------------------------------------
// k_mm2 v3 (persistent MFMA): each wave loops over slabs (16 H rows each).
//   Whi: preloaded in VGPRs ONCE (persistent loop forces residency).
//   Wlo: one padded LDS copy per block (row pad +8 shorts => 2-way, free).
//   D = ahi@Whi + alo@Whi + ahi@Wlo   (H exact via hi/lo split).
// ---------------------------------------------------------------------------
#define MM2_WAVES 2048  // 512 blocks x 4 waves
__global__ __launch_bounds__(256, 2) void k_mm2(const float* __restrict__ B_,
                                                const int* __restrict__ x,
                                                const float* __restrict__ U1,
                                                const float* __restrict__ U2c,
                                                const short* __restrict__ Wt,
                                                const short* __restrict__ Wlo,
                                                const float* __restrict__ bu2,
                                                __hip_bfloat16* __restrict__ M) {
  __shared__ short wlo[128 * 136];
  int t = threadIdx.x;
  // stage Wlo into LDS (2048 chunks of 8 shorts)
  for (int c = t; c < 2048; c += 256) {
    int r = c >> 4, q = c & 15;
    *(short8*)&wlo[r * 136 + q * 8] = *(const short8*)&Wlo[r * 128 + q * 8];
  }

  int lane = t & 63;
  int m = lane & 15;
  int quad = lane >> 4;
  int wid = blockIdx.x * 4 + (t >> 6);

  // preload hi B-fragments (128 VGPRs) + bias, once
  short8 bf[4][8];
#pragma unroll
  for (int kc = 0; kc < 4; kc++)
#pragma unroll
    for (int nt = 0; nt < 8; nt++)
      bf[kc][nt] = *(const short8*)&Wt[(nt * 16 + m) * 128 + kc * 32 + quad * 8];
  float bias[8];
#pragma unroll
  for (int nt = 0; nt < 8; nt++) bias[nt] = bu2[nt * 16 + m];

  __syncthreads();

  for (int s = wid; s < 12500; s += MM2_WAVES) {
    int node = s * 4 + (m >> 2);
    int attr = m & 3;
    int xn = x[node];
    f32x4 acc[8];
#pragma unroll
    for (int nt = 0; nt < 8; nt++) acc[nt] = (f32x4){0.f, 0.f, 0.f, 0.f};

#pragma unroll
    for (int kc = 0; kc < 4; kc++) {
      int k0 = kc * 32 + quad * 8;
      short8 ahi, alo;
      {
        float u1a[8], bba[8], u2a[8];
        *(float4*)&u1a[0] = *(const float4*)&U1[xn * 128 + k0];
        *(float4*)&u1a[4] = *(const float4*)&U1[xn * 128 + k0 + 4];
        *(float4*)&bba[0] = *(const float4*)&B_[node * 128 + k0];
        *(float4*)&bba[4] = *(const float4*)&B_[node * 128 + k0 + 4];
        *(float4*)&u2a[0] = *(const float4*)&U2c[attr * 128 + k0];
        *(float4*)&u2a[4] = *(const float4*)&U2c[attr * 128 + k0 + 4];
#pragma unroll
        for (int j = 0; j < 8; j++) {
          float h = u1a[j] + bba[j] + u2a[j];
          h = h > 0.f ? h : 0.f;
          bfbits hi; hi.b = __float2bfloat16(h);
          float hf = __bfloat162float(hi.b);
          bfbits lo; lo.b = __float2bfloat16(h - hf);
          ahi[j] = hi.s;
          alo[j] = lo.s;
        }
      }
      short8 lf[8];
#pragma unroll
      for (int nt = 0; nt < 8; nt++)
        lf[nt] = *(const short8*)&wlo[(nt * 16 + m) * 136 + kc * 32 + quad * 8];
#pragma unroll
      for (int nt = 0; nt < 8; nt++) {
        acc[nt] = __builtin_amdgcn_mfma_f32_16x16x32_bf16(ahi, bf[kc][nt], acc[nt], 0, 0, 0);
        acc[nt] = __builtin_amdgcn_mfma_f32_16x16x32_bf16(alo, bf[kc][nt], acc[nt], 0, 0, 0);
        acc[nt] = __builtin_amdgcn_mfma_f32_16x16x32_bf16(ahi, lf[nt], acc[nt], 0, 0, 0);
      }
    }

    int rbase = s * 16;
#pragma unroll
    for (int nt = 0; nt < 8; nt++) {
#pragma unroll
      for (int r = 0; r < 4; r++) {
        float v = acc[nt][r] + bias[nt];
        v = v > 0.f ? v : 0.f;
        M[(rbase + quad * 4 + r) * 128 + nt * 16 + m] = __float2bfloat16(v);
      }
    }
  }
}

// ---------------------------------------------------------------------------
// mol_state[batch[n]] += node_state[n]
// ---------------------------------------------------------------------------
__global__ void k_mol(const float* __restrict__ node,
                      const int* __restrict__ batch,
                      float* __restrict__ mol) {
  int idx = blockIdx.x * 256 + threadIdx.x;
  int n = idx >> 7;
  int c = idx & 127;
  atomicAdd(&mol[batch[n] * 128 + c], node[idx]);
}

// ---------------------------------------------------------------------------
// out[m] = relu(mol[m] @ Wr1 + br1) @ Wr2 + br2
// ---------------------------------------------------------------------------
__global__ __launch_bounds__(256) void k_readout(const float* __restrict__ mol,
                                                 const float* __restrict__ Wr1,
                                                 const float* __restrict__ br1,
                                                 const float* __restrict__ Wr2,
                                                 const float* __restrict__ br2,
                                                 float* __restrict__ out) {
  int m = blockIdx.x;
  __shared__ float ms[128];
  __shared__ float red[256];
  int t = threadIdx.x;
  if (t < 128) ms[t] = mol[m * 128 + t];
  __syncthreads();
  float part = 0.f;
#pragma unroll
  for (int jj = 0; jj < 2; jj++) {
    int j = t + jj * 256;
    float acc = br1[j];
#pragma unroll
    for (int k = 0; k < 128; k += 4) {
      float4 m4 = *(const float4*)&ms[k];
      acc += m4.x * Wr1[k * 512 + j] + m4.y * Wr1[(k + 1) * 512 + j] +
             m4.z * Wr1[(k + 2) * 512 + j] + m4.w * Wr1[(k + 3) * 512 + j];
    }
    acc = acc > 0.f ? acc : 0.f;
    part += acc * Wr2[j];
  }
  red[t] = part;
  __syncthreads();
  for (int s = 128; s > 0; s >>= 1) {
    if (t < s) red[t] += red[t + s];
    __syncthreads();
  }
  if (t == 0) out[m] = red[0] + br2[0];
}

// ---------------------------------------------------------------------------
extern "C" void kernel_launch(void* const* d_in, const int* in_sizes, int n_in,
                              void* d_out, int out_size, void* d_ws, size_t ws_size,
                              hipStream_t stream) {
  const int* x        = (const int*)d_in[0];
  const int* eattr    = (const int*)d_in[1];
  const int* eidx     = (const int*)d_in[2];
  const int* batch    = (const int*)d_in[3];
  const float* atom_table = (const float*)d_in[4];
  const float* bond_table = (const float*)d_in[5];
  const float* Wi  = (const float*)d_in[6];
  const float* bi  = (const float*)d_in[7];
  const float* Wu1 = (const float*)d_in[8];
  const float* bu1 = (const float*)d_in[9];
  const float* Wu2 = (const float*)d_in[10];
  const float* bu2 = (const float*)d_in[11];
  const float* Wr1 = (const float*)d_in[12];
  const float* br1 = (const float*)d_in[13];
  const float* Wr2 = (const float*)d_in[14];
  const float* br2 = (const float*)d_in[15];
  float* out = (float*)d_out;

  char* ws = (char*)d_ws;
  __hip_bfloat16* M = (__hip_bfloat16*)(ws);       //  51,200,000 B (bf16)
  short* Wt     = (short*)(ws + 51200000);         //      32,768 B (bf16 Wu2^T hi)
  short* Wlo    = (short*)(ws + 51232768);         //      32,768 B (bf16 Wu2^T lo)
  float* A      = (float*)(ws + 102400000);        //  25,600,000 B
  float* B      = (float*)(ws + 128000000);        //  25,600,000 B
  int*   csr    = (int*)  (ws + 153600000);        //   3,200,000 B
  int*   rowptr = (int*)  (ws + 156800000);        //     200,064 B
  float* T1     = (float*)(ws + 157000064);        //      60,928 B
  float* U1     = (float*)(ws + 157060992);        //      60,928 B
  float* T2c    = (float*)(ws + 157121920);        //       2,048 B
  float* U2c    = (float*)(ws + 157123968);        //       2,048 B
  float* TT     = (float*)(ws + 157126016);        //     243,712 B
  float* mol    = (float*)(ws + 157369728);        //   1,024,000 B
  // cnt/cursor alias B: only live before the first k_mm1 write to B.
  int*   cnt    = (int*)B;
  int*   cursor = (int*)(ws + 128000000 + 204800);

  hipMemsetAsync(cnt, 0, N_NODES * sizeof(int), stream);
  k_tables<<<123, 128, 0, stream>>>(atom_table, bond_table, Wi, bi, Wu1, bu1,
                                    T1, U1, T2c, U2c);
  k_tt<<<476, 128, 0, stream>>>(T1, T2c, TT);
  k_wt<<<128, 128, 0, stream>>>(Wu2, Wt, Wlo);
  k_hist<<<N_EDGES / 256, 256, 0, stream>>>(eidx, cnt);
  k_scan<<<1, 1024, 0, stream>>>(cnt, rowptr, cursor);
  k_fill<<<N_EDGES / 256, 256, 0, stream>>>(eidx, eattr, cursor, csr);

  k_gather0<<<N_NODES / 4, 256, 0, stream>>>(rowptr, csr, x, TT, A);

  for (int p = 0; p < 4; p++) {
    k_mm1<<<(N_NODES + 63) / 64, 256, 0, stream>>>(A, Wu1, B);
    k_mm2<<<512, 256, 0, stream>>>(B, x, U1, U2c, Wt, Wlo, bu2, M);
    k_gather<<<N_NODES / 4, 256, 0, stream>>>(rowptr, csr, M, A);
  }

  hipMemsetAsync(mol, 0, NUM_MOL * 128 * sizeof(float), stream);
  k_mol<<<(N_NODES * 128) / 256, 256, 0, stream>>>(A, batch, mol);
  k_readout<<<NUM_MOL, 256, 0, stream>>>(mol, Wr1, br1, Wr2, br2, out);
}

// Round 8
// 936.489 us; speedup vs baseline: 1.2934x; 1.2108x over previous
//
#include <hip/hip_runtime.h>
#include <hip/hip_bf16.h>

#define N_NODES 50000
#define N_EDGES 800000
#define NUM_MOL 2000

typedef __attribute__((ext_vector_type(8))) short short8;
typedef __attribute__((ext_vector_type(4))) float f32x4;

union bfbits { __hip_bfloat16 b; short s; };

// ---------------------------------------------------------------------------
// Type tables:
//   T1[t,c]  = atom_table[t,:] @ Wi[0:128,c]            (119x128)
//   T2c[a,c] = bond_table[a,:] @ Wi[128:192,c] + bi[c]  (4x128)
//   U1[t,c]  = atom_table[t,:] @ Wu1[0:128,c]           (119x128)
//   U2c[a,c] = bond_table[a,:] @ Wu1[128:192,c] + bu1[c](4x128)
// ---------------------------------------------------------------------------
__global__ void k_tables(const float* __restrict__ atom_table,
                         const float* __restrict__ bond_table,
                         const float* __restrict__ Wi,
                         const float* __restrict__ bi,
                         const float* __restrict__ Wu1,
                         const float* __restrict__ bu1,
                         float* __restrict__ T1, float* __restrict__ U1,
                         float* __restrict__ T2c, float* __restrict__ U2c) {
  int b = blockIdx.x;
  int c = threadIdx.x;
  if (b < 119) {
    float t = 0.f, u = 0.f;
    for (int k = 0; k < 128; k++) {
      float a = atom_table[b * 128 + k];
      t += a * Wi[k * 128 + c];
      u += a * Wu1[k * 128 + c];
    }
    T1[b * 128 + c] = t;
    U1[b * 128 + c] = u;
  } else {
    int a = b - 119;
    float t = bi[c], u = bu1[c];
    for (int k = 0; k < 64; k++) {
      float bv = bond_table[a * 64 + k];
      t += bv * Wi[(128 + k) * 128 + c];
      u += bv * Wu1[(128 + k) * 128 + c];
    }
    T2c[a * 128 + c] = t;
    U2c[a * 128 + c] = u;
  }
}

// TT[x*4+a, c] = relu(T1[x,c] + T2c[a,c])
__global__ void k_tt(const float* __restrict__ T1, const float* __restrict__ T2c,
                     float* __restrict__ TT) {
  int r = blockIdx.x;   // 0..475
  int c = threadIdx.x;
  float v = T1[(r >> 2) * 128 + c] + T2c[(r & 3) * 128 + c];
  TT[r * 128 + c] = v > 0.f ? v : 0.f;
}

// Wt[n][k]  = bf16(Wu2[k][n])            (hi, transposed for B-frags)
// Wlo[n][k] = bf16(Wu2[k][n] - fp32(Wt)) (lo residual)
__global__ void k_wt(const float* __restrict__ Wu2, short* __restrict__ Wt,
                     short* __restrict__ Wlo) {
  int n = blockIdx.x;
  int k = threadIdx.x;
  float w = Wu2[k * 128 + n];
  bfbits hi; hi.b = __float2bfloat16(w);
  float hf = __bfloat162float(hi.b);
  bfbits lo; lo.b = __float2bfloat16(w - hf);
  Wt[n * 128 + k] = hi.s;
  Wlo[n * 128 + k] = lo.s;
}

// ---------------------------------------------------------------------------
// CSR build: histogram of dst, single-block scan, fill.
// ---------------------------------------------------------------------------
__global__ void k_hist(const int* __restrict__ eidx, int* __restrict__ cnt) {
  int e = blockIdx.x * 256 + threadIdx.x;
  atomicAdd(&cnt[eidx[N_EDGES + e]], 1);
}

__global__ __launch_bounds__(1024) void k_scan(const int* __restrict__ cnt,
                                               int* __restrict__ rowptr,
                                               int* __restrict__ cursor) {
  __shared__ int buf[1024];
  __shared__ int carry_s;
  int t = threadIdx.x;
  if (t == 0) carry_s = 0;
  __syncthreads();
  for (int base = 0; base < N_NODES; base += 1024) {
    int i = base + t;
    int v = (i < N_NODES) ? cnt[i] : 0;
    buf[t] = v;
    __syncthreads();
    for (int off = 1; off < 1024; off <<= 1) {
      int add = (t >= off) ? buf[t - off] : 0;
      __syncthreads();
      buf[t] += add;
      __syncthreads();
    }
    int carry = carry_s;
    if (i < N_NODES) {
      rowptr[i + 1] = carry + buf[t];
      cursor[i] = carry + buf[t] - v;   // exclusive prefix
    }
    __syncthreads();
    if (t == 1023) carry_s = carry + buf[1023];
    __syncthreads();
  }
  if (t == 0) rowptr[0] = 0;
}

__global__ void k_fill(const int* __restrict__ eidx, const int* __restrict__ attr,
                       int* __restrict__ cursor, int* __restrict__ csr) {
  int e = blockIdx.x * 256 + threadIdx.x;
  int d = eidx[N_EDGES + e];
  int pos = atomicAdd(&cursor[d], 1);
  csr[pos] = eidx[e] * 4 + attr[e];
}

// ---------------------------------------------------------------------------
// Gather initial messages: A[n] = sum_{edges into n} TT[x[src]*4+attr]  (fp32)
// ---------------------------------------------------------------------------
__global__ void k_gather0(const int* __restrict__ rowptr, const int* __restrict__ csr,
                          const int* __restrict__ x, const float* __restrict__ TT,
                          float* __restrict__ A_) {
  int n = blockIdx.x * 4 + (threadIdx.x >> 6);
  int lane = threadIdx.x & 63;
  int beg = rowptr[n], end = rowptr[n + 1];
  float ax = 0.f, ay = 0.f;
  int i = beg;
  for (; i + 3 < end; i += 4) {
    int m0 = csr[i], m1 = csr[i + 1], m2 = csr[i + 2], m3 = csr[i + 3];
    int t0 = x[m0 >> 2] * 4 + (m0 & 3);
    int t1 = x[m1 >> 2] * 4 + (m1 & 3);
    int t2 = x[m2 >> 2] * 4 + (m2 & 3);
    int t3 = x[m3 >> 2] * 4 + (m3 & 3);
    float2 v0 = *(const float2*)&TT[t0 * 128 + lane * 2];
    float2 v1 = *(const float2*)&TT[t1 * 128 + lane * 2];
    float2 v2 = *(const float2*)&TT[t2 * 128 + lane * 2];
    float2 v3 = *(const float2*)&TT[t3 * 128 + lane * 2];
    ax += (v0.x + v1.x) + (v2.x + v3.x);
    ay += (v0.y + v1.y) + (v2.y + v3.y);
  }
  for (; i < end; i++) {
    int m0 = csr[i];
    int t0 = x[m0 >> 2] * 4 + (m0 & 3);
    float2 v0 = *(const float2*)&TT[t0 * 128 + lane * 2];
    ax += v0.x;
    ay += v0.y;
  }
  float2 o; o.x = ax; o.y = ay;
  *(float2*)&A_[n * 128 + lane * 2] = o;
}

// ---------------------------------------------------------------------------
// Gather messages: A[n] = sum_{edges into n} M_bf16[src*4+attr], 4-deep unroll.
// ---------------------------------------------------------------------------
__global__ void k_gather(const int* __restrict__ rowptr, const int* __restrict__ csr,
                         const __hip_bfloat16* __restrict__ M, float* __restrict__ A_) {
  int n = blockIdx.x * 4 + (threadIdx.x >> 6);
  int lane = threadIdx.x & 63;
  int beg = rowptr[n], end = rowptr[n + 1];
  float ax = 0.f, ay = 0.f;
  int i = beg;
  for (; i + 3 < end; i += 4) {
    int m0 = csr[i], m1 = csr[i + 1], m2 = csr[i + 2], m3 = csr[i + 3];
    float2 v0 = __bfloat1622float2(*(const __hip_bfloat162*)&M[m0 * 128 + lane * 2]);
    float2 v1 = __bfloat1622float2(*(const __hip_bfloat162*)&M[m1 * 128 + lane * 2]);
    float2 v2 = __bfloat1622float2(*(const __hip_bfloat162*)&M[m2 * 128 + lane * 2]);
    float2 v3 = __bfloat1622float2(*(const __hip_bfloat162*)&M[m3 * 128 + lane * 2]);
    ax += (v0.x + v1.x) + (v2.x + v3.x);
    ay += (v0.y + v1.y) + (v2.y + v3.y);
  }
  for (; i < end; i++) {
    int m0 = csr[i];
    float2 v0 = __bfloat1622float2(*(const __hip_bfloat162*)&M[m0 * 128 + lane * 2]);
    ax += v0.x;
    ay += v0.y;
  }
  float2 o; o.x = ax; o.y = ay;
  *(float2*)&A_[n * 128 + lane * 2] = o;
}

// ---------------------------------------------------------------------------
// k_mm1: B = A @ Wu1[192:320,:]  fp32 tiled GEMM (kept fp32 for accuracy).
// ---------------------------------------------------------------------------
__global__ __launch_bounds__(256, 4) void k_mm1(const float* __restrict__ A_,
                                                const float* __restrict__ Wu1,
                                                float* __restrict__ B_) {
  __shared__ float Hs[64][132];
  int t = threadIdx.x;
  int base = blockIdx.x * 64;
#pragma unroll
  for (int j = 0; j < 8; j++) {
    int idx = j * 256 + t;        // 0..2047 float4 slots
    int rr = idx >> 5;            // local row
    int kq = idx & 31;            // float4 index in k
    int n = base + rr;
    if (n >= N_NODES) n = N_NODES - 1;
    float4 v = *(const float4*)&A_[n * 128 + kq * 4];
    *(float4*)&Hs[rr][kq * 4] = v;
  }
  __syncthreads();
  int r0 = (t >> 4) * 4;
  int c0 = (t & 15) * 8;
  const float* W = Wu1 + 192 * 128;
  float acc[4][8];
#pragma unroll
  for (int r = 0; r < 4; r++)
#pragma unroll
    for (int j = 0; j < 8; j++) acc[r][j] = 0.f;
#pragma unroll 2
  for (int kq = 0; kq < 32; kq++) {
    const int k = kq * 4;
    float h0[4], h1[4], h2[4], h3[4];
    *(float4*)h0 = *(const float4*)&Hs[r0][k];
    *(float4*)h1 = *(const float4*)&Hs[r0 + 1][k];
    *(float4*)h2 = *(const float4*)&Hs[r0 + 2][k];
    *(float4*)h3 = *(const float4*)&Hs[r0 + 3][k];
#pragma unroll
    for (int i = 0; i < 4; i++) {
      float w[8];
      *(float4*)&w[0] = *(const float4*)&W[(k + i) * 128 + c0];
      *(float4*)&w[4] = *(const float4*)&W[(k + i) * 128 + c0 + 4];
      float hv[4] = {h0[i], h1[i], h2[i], h3[i]};
#pragma unroll
      for (int r = 0; r < 4; r++)
#pragma unroll
        for (int j = 0; j < 8; j++) acc[r][j] += hv[r] * w[j];
    }
  }
#pragma unroll
  for (int r = 0; r < 4; r++) {
    int n = base + r0 + r;
    if (n < N_NODES) {
      float4 o0, o1;
      o0.x = acc[r][0]; o0.y = acc[r][1]; o0.z = acc[r][2]; o0.w = acc[r][3];
      o1.x = acc[r][4]; o1.y = acc[r][5]; o1.z = acc[r][6]; o1.w = acc[r][7];
      *(float4*)&B_[n * 128 + c0] = o0;
      *(float4*)&B_[n * 128 + c0 + 4] = o1;
    }
  }
}

// ---------------------------------------------------------------------------
// k_mm2 v4 (wave-pair MFMA): each slab (16 H rows) is computed by TWO waves,
// each owning 64 channels (4 n-tiles). Whi AND Wlo live in VGPRs (64+64) —
// no LDS weights, no conflicts. Epilogue bounces acc through an 8.4 KB LDS
// tile and stores M as contiguous 16 B/lane chunks (full lines, no
// write-amp). Block = 4 waves = 2 slabs per iteration; grid 1024; 7 iters.
//   D = ahi@Whi + alo@Whi + ahi@Wlo   (H exact via hi/lo split).
// ---------------------------------------------------------------------------
__global__ __launch_bounds__(256, 2) void k_mm2(const float* __restrict__ B_,
                                                const int* __restrict__ x,
                                                const float* __restrict__ U1,
                                                const float* __restrict__ U2c,
                                                const short* __restrict__ Wt,
                                                const short* __restrict__ Wlo,
                                                const float* __restrict__ bu2,
                                                __hip_bfloat16* __restrict__ M) {
  __shared__ short mbuf[2][16][132];
  int t = threadIdx.x;
  int lane = t & 63;
  int m = lane & 15;
  int quad = lane >> 4;
  int wid = t >> 6;        // 0..3
  int pairid = wid >> 1;   // which slab of the block's pair
  int h = wid & 1;         // channel half (0: ch 0-63, 1: ch 64-127)

  // per-wave weights in VGPRs: 4 kc x 4 nt, hi + lo = 128 VGPRs
  short8 whi[4][4], wlo[4][4];
#pragma unroll
  for (int kc = 0; kc < 4; kc++)
#pragma unroll
    for (int nt = 0; nt < 4; nt++) {
      int n = h * 64 + nt * 16 + m;
      whi[kc][nt] = *(const short8*)&Wt[n * 128 + kc * 32 + quad * 8];
      wlo[kc][nt] = *(const short8*)&Wlo[n * 128 + kc * 32 + quad * 8];
    }
  float bias[4];
#pragma unroll
  for (int nt = 0; nt < 4; nt++) bias[nt] = bu2[h * 64 + nt * 16 + m];

  for (int iter = 0; iter < 7; iter++) {
    int s = iter * 2048 + blockIdx.x * 2 + pairid;
    if (s < 12500) {
      int node = s * 4 + (m >> 2);
      int attr = m & 3;
      int xn = x[node];
      f32x4 acc[4];
#pragma unroll
      for (int nt = 0; nt < 4; nt++) acc[nt] = (f32x4){0.f, 0.f, 0.f, 0.f};

#pragma unroll
      for (int kc = 0; kc < 4; kc++) {
        int k0 = kc * 32 + quad * 8;
        short8 ahi, alo;
        {
          float u1a[8], bba[8], u2a[8];
          *(float4*)&u1a[0] = *(const float4*)&U1[xn * 128 + k0];
          *(float4*)&u1a[4] = *(const float4*)&U1[xn * 128 + k0 + 4];
          *(float4*)&bba[0] = *(const float4*)&B_[node * 128 + k0];
          *(float4*)&bba[4] = *(const float4*)&B_[node * 128 + k0 + 4];
          *(float4*)&u2a[0] = *(const float4*)&U2c[attr * 128 + k0];
          *(float4*)&u2a[4] = *(const float4*)&U2c[attr * 128 + k0 + 4];
#pragma unroll
          for (int j = 0; j < 8; j++) {
            float hv = u1a[j] + bba[j] + u2a[j];
            hv = hv > 0.f ? hv : 0.f;
            bfbits hi; hi.b = __float2bfloat16(hv);
            float hf = __bfloat162float(hi.b);
            bfbits lo; lo.b = __float2bfloat16(hv - hf);
            ahi[j] = hi.s;
            alo[j] = lo.s;
          }
        }
#pragma unroll
        for (int nt = 0; nt < 4; nt++) {
          acc[nt] = __builtin_amdgcn_mfma_f32_16x16x32_bf16(ahi, whi[kc][nt], acc[nt], 0, 0, 0);
          acc[nt] = __builtin_amdgcn_mfma_f32_16x16x32_bf16(alo, whi[kc][nt], acc[nt], 0, 0, 0);
          acc[nt] = __builtin_amdgcn_mfma_f32_16x16x32_bf16(ahi, wlo[kc][nt], acc[nt], 0, 0, 0);
        }
      }

      // acc -> LDS (bf16), rows = quad*4+r, cols = h*64 + nt*16 + m
#pragma unroll
      for (int nt = 0; nt < 4; nt++) {
#pragma unroll
        for (int r = 0; r < 4; r++) {
          float v = acc[nt][r] + bias[nt];
          v = v > 0.f ? v : 0.f;
          bfbits o; o.b = __float2bfloat16(v);
          mbuf[pairid][quad * 4 + r][h * 64 + nt * 16 + m] = o.s;
        }
      }
    }
    __syncthreads();
    // coalesced store: 32 rows x 256 B = 512 chunks of 16 B
#pragma unroll
    for (int p = 0; p < 2; p++) {
      int chunk = p * 256 + t;
      int row = chunk >> 4;          // 0..31
      int sg = iter * 2048 + blockIdx.x * 2 + (row >> 4);
      if (sg < 12500) {
        int r = row & 15;
        short8 v = *(const short8*)&mbuf[row >> 4][r][(chunk & 15) * 8];
        *(short8*)((short*)M + (sg * 16 + r) * 128 + (chunk & 15) * 8) = v;
      }
    }
    __syncthreads();
  }
}

// ---------------------------------------------------------------------------
// mol_state[batch[n]] += node_state[n]
// ---------------------------------------------------------------------------
__global__ void k_mol(const float* __restrict__ node,
                      const int* __restrict__ batch,
                      float* __restrict__ mol) {
  int idx = blockIdx.x * 256 + threadIdx.x;
  int n = idx >> 7;
  int c = idx & 127;
  atomicAdd(&mol[batch[n] * 128 + c], node[idx]);
}

// ---------------------------------------------------------------------------
// out[m] = relu(mol[m] @ Wr1 + br1) @ Wr2 + br2
// ---------------------------------------------------------------------------
__global__ __launch_bounds__(256) void k_readout(const float* __restrict__ mol,
                                                 const float* __restrict__ Wr1,
                                                 const float* __restrict__ br1,
                                                 const float* __restrict__ Wr2,
                                                 const float* __restrict__ br2,
                                                 float* __restrict__ out) {
  int m = blockIdx.x;
  __shared__ float ms[128];
  __shared__ float red[256];
  int t = threadIdx.x;
  if (t < 128) ms[t] = mol[m * 128 + t];
  __syncthreads();
  float part = 0.f;
#pragma unroll
  for (int jj = 0; jj < 2; jj++) {
    int j = t + jj * 256;
    float acc = br1[j];
#pragma unroll
    for (int k = 0; k < 128; k += 4) {
      float4 m4 = *(const float4*)&ms[k];
      acc += m4.x * Wr1[k * 512 + j] + m4.y * Wr1[(k + 1) * 512 + j] +
             m4.z * Wr1[(k + 2) * 512 + j] + m4.w * Wr1[(k + 3) * 512 + j];
    }
    acc = acc > 0.f ? acc : 0.f;
    part += acc * Wr2[j];
  }
  red[t] = part;
  __syncthreads();
  for (int s = 128; s > 0; s >>= 1) {
    if (t < s) red[t] += red[t + s];
    __syncthreads();
  }
  if (t == 0) out[m] = red[0] + br2[0];
}

// ---------------------------------------------------------------------------
extern "C" void kernel_launch(void* const* d_in, const int* in_sizes, int n_in,
                              void* d_out, int out_size, void* d_ws, size_t ws_size,
                              hipStream_t stream) {
  const int* x        = (const int*)d_in[0];
  const int* eattr    = (const int*)d_in[1];
  const int* eidx     = (const int*)d_in[2];
  const int* batch    = (const int*)d_in[3];
  const float* atom_table = (const float*)d_in[4];
  const float* bond_table = (const float*)d_in[5];
  const float* Wi  = (const float*)d_in[6];
  const float* bi  = (const float*)d_in[7];
  const float* Wu1 = (const float*)d_in[8];
  const float* bu1 = (const float*)d_in[9];
  const float* Wu2 = (const float*)d_in[10];
  const float* bu2 = (const float*)d_in[11];
  const float* Wr1 = (const float*)d_in[12];
  const float* br1 = (const float*)d_in[13];
  const float* Wr2 = (const float*)d_in[14];
  const float* br2 = (const float*)d_in[15];
  float* out = (float*)d_out;

  char* ws = (char*)d_ws;
  __hip_bfloat16* M = (__hip_bfloat16*)(ws);       //  51,200,000 B (bf16)
  short* Wt     = (short*)(ws + 51200000);         //      32,768 B (bf16 Wu2^T hi)
  short* Wlo    = (short*)(ws + 51232768);         //      32,768 B (bf16 Wu2^T lo)
  float* A      = (float*)(ws + 102400000);        //  25,600,000 B
  float* B      = (float*)(ws + 128000000);        //  25,600,000 B
  int*   csr    = (int*)  (ws + 153600000);        //   3,200,000 B
  int*   rowptr = (int*)  (ws + 156800000);        //     200,064 B
  float* T1     = (float*)(ws + 157000064);        //      60,928 B
  float* U1     = (float*)(ws + 157060992);        //      60,928 B
  float* T2c    = (float*)(ws + 157121920);        //       2,048 B
  float* U2c    = (float*)(ws + 157123968);        //       2,048 B
  float* TT     = (float*)(ws + 157126016);        //     243,712 B
  float* mol    = (float*)(ws + 157369728);        //   1,024,000 B
  // cnt/cursor alias B: only live before the first k_mm1 write to B.
  int*   cnt    = (int*)B;
  int*   cursor = (int*)(ws + 128000000 + 204800);

  hipMemsetAsync(cnt, 0, N_NODES * sizeof(int), stream);
  k_tables<<<123, 128, 0, stream>>>(atom_table, bond_table, Wi, bi, Wu1, bu1,
                                    T1, U1, T2c, U2c);
  k_tt<<<476, 128, 0, stream>>>(T1, T2c, TT);
  k_wt<<<128, 128, 0, stream>>>(Wu2, Wt, Wlo);
  k_hist<<<N_EDGES / 256, 256, 0, stream>>>(eidx, cnt);
  k_scan<<<1, 1024, 0, stream>>>(cnt, rowptr, cursor);
  k_fill<<<N_EDGES / 256, 256, 0, stream>>>(eidx, eattr, cursor, csr);

  k_gather0<<<N_NODES / 4, 256, 0, stream>>>(rowptr, csr, x, TT, A);

  for (int p = 0; p < 4; p++) {
    k_mm1<<<(N_NODES + 63) / 64, 256, 0, stream>>>(A, Wu1, B);
    k_mm2<<<1024, 256, 0, stream>>>(B, x, U1, U2c, Wt, Wlo, bu2, M);
    k_gather<<<N_NODES / 4, 256, 0, stream>>>(rowptr, csr, M, A);
  }

  hipMemsetAsync(mol, 0, NUM_MOL * 128 * sizeof(float), stream);
  k_mol<<<(N_NODES * 128) / 256, 256, 0, stream>>>(A, batch, mol);
  k_readout<<<NUM_MOL, 256, 0, stream>>>(mol, Wr1, br1, Wr2, br2, out);
}

// Round 9
// 838.047 us; speedup vs baseline: 1.4453x; 1.1175x over previous
//
#include <hip/hip_runtime.h>
#include <hip/hip_bf16.h>

#define N_NODES 50000
#define N_EDGES 800000
#define NUM_MOL 2000

typedef __attribute__((ext_vector_type(8))) short short8;
typedef __attribute__((ext_vector_type(4))) float f32x4;

union bfbits { __hip_bfloat16 b; short s; };

// ---------------------------------------------------------------------------
// Type tables.
// ---------------------------------------------------------------------------
__global__ void k_tables(const float* __restrict__ atom_table,
                         const float* __restrict__ bond_table,
                         const float* __restrict__ Wi,
                         const float* __restrict__ bi,
                         const float* __restrict__ Wu1,
                         const float* __restrict__ bu1,
                         float* __restrict__ T1, float* __restrict__ U1,
                         float* __restrict__ T2c, float* __restrict__ U2c) {
  int b = blockIdx.x;
  int c = threadIdx.x;
  if (b < 119) {
    float t = 0.f, u = 0.f;
    for (int k = 0; k < 128; k++) {
      float a = atom_table[b * 128 + k];
      t += a * Wi[k * 128 + c];
      u += a * Wu1[k * 128 + c];
    }
    T1[b * 128 + c] = t;
    U1[b * 128 + c] = u;
  } else {
    int a = b - 119;
    float t = bi[c], u = bu1[c];
    for (int k = 0; k < 64; k++) {
      float bv = bond_table[a * 64 + k];
      t += bv * Wi[(128 + k) * 128 + c];
      u += bv * Wu1[(128 + k) * 128 + c];
    }
    T2c[a * 128 + c] = t;
    U2c[a * 128 + c] = u;
  }
}

// TT[x*4+a, c] = relu(T1[x,c] + T2c[a,c])
__global__ void k_tt(const float* __restrict__ T1, const float* __restrict__ T2c,
                     float* __restrict__ TT) {
  int r = blockIdx.x;   // 0..475
  int c = threadIdx.x;
  float v = T1[(r >> 2) * 128 + c] + T2c[(r & 3) * 128 + c];
  TT[r * 128 + c] = v > 0.f ? v : 0.f;
}

// Wt/Wlo: hi/lo bf16 split of Wu2^T for MFMA B-frags.
__global__ void k_wt(const float* __restrict__ Wu2, short* __restrict__ Wt,
                     short* __restrict__ Wlo) {
  int n = blockIdx.x;
  int k = threadIdx.x;
  float w = Wu2[k * 128 + n];
  bfbits hi; hi.b = __float2bfloat16(w);
  float hf = __bfloat162float(hi.b);
  bfbits lo; lo.b = __float2bfloat16(w - hf);
  Wt[n * 128 + k] = hi.s;
  Wlo[n * 128 + k] = lo.s;
}

// ---------------------------------------------------------------------------
// CSR build: histogram, 3-phase multi-block scan, fill (csr + csr0).
// ---------------------------------------------------------------------------
__global__ void k_hist(const int* __restrict__ eidx, int* __restrict__ cnt) {
  int e = blockIdx.x * 256 + threadIdx.x;
  atomicAdd(&cnt[eidx[N_EDGES + e]], 1);
}

// phase A: 49 blocks x 1024 — block-local inclusive scan + block totals
__global__ __launch_bounds__(1024) void k_scanA(const int* __restrict__ cnt,
                                                int* __restrict__ locinc,
                                                int* __restrict__ partial) {
  __shared__ int buf[1024];
  int t = threadIdx.x;
  int i = blockIdx.x * 1024 + t;
  int v = (i < N_NODES) ? cnt[i] : 0;
  buf[t] = v;
  __syncthreads();
  for (int off = 1; off < 1024; off <<= 1) {
    int add = (t >= off) ? buf[t - off] : 0;
    __syncthreads();
    buf[t] += add;
    __syncthreads();
  }
  if (i < N_NODES) locinc[i] = buf[t];
  if (t == 1023) partial[blockIdx.x] = buf[t];
}

// phase B: one wave scans the 49 block totals
__global__ void k_scanB(const int* __restrict__ partial, int* __restrict__ offs) {
  int lane = threadIdx.x;   // 64 threads
  int v = (lane < 49) ? partial[lane] : 0;
  int inc = v;
  for (int d = 1; d < 64; d <<= 1) {
    int u = __shfl_up(inc, d, 64);
    if (lane >= d) inc += u;
  }
  if (lane < 49) offs[lane] = inc - v;   // exclusive
}

// phase C: apply offsets -> rowptr (inclusive at i+1) and cursor (exclusive)
__global__ void k_scanC(const int* __restrict__ cnt, const int* __restrict__ locinc,
                        const int* __restrict__ offs,
                        int* __restrict__ rowptr, int* __restrict__ cursor) {
  int i = blockIdx.x * 256 + threadIdx.x;
  if (i < N_NODES) {
    int rp = locinc[i] + offs[i >> 10];
    rowptr[i + 1] = rp;
    cursor[i] = rp - cnt[i];
    if (i == 0) rowptr[0] = 0;
  }
}

// csr[pos] = src*4+attr ; csr0[pos] = x[src]*4+attr (kills x-indirection in gather0)
__global__ void k_fill(const int* __restrict__ eidx, const int* __restrict__ attr,
                       const int* __restrict__ x,
                       int* __restrict__ cursor, int* __restrict__ csr,
                       int* __restrict__ csr0) {
  int e = blockIdx.x * 256 + threadIdx.x;
  int d = eidx[N_EDGES + e];
  int s = eidx[e];
  int a = attr[e];
  int pos = atomicAdd(&cursor[d], 1);
  csr[pos] = s * 4 + a;
  csr0[pos] = x[s] * 4 + a;
}

// molptr[m] = lower_bound(batch, m)  (batch is sorted)
__global__ void k_molptr(const int* __restrict__ batch, int* __restrict__ molptr) {
  int m = blockIdx.x * 256 + threadIdx.x;
  if (m > NUM_MOL) return;
  int lo = 0, hi = N_NODES;
  while (lo < hi) {
    int mid = (lo + hi) >> 1;
    if (batch[mid] < m) lo = mid + 1; else hi = mid;
  }
  molptr[m] = lo;
}

// ---------------------------------------------------------------------------
// Gather initial messages: A[n] = sum TT[csr0[i]]   (fp32 rows, 512 B)
// int4-batched wave-uniform index reads + 8-deep row loads.
// ---------------------------------------------------------------------------
__global__ void k_gather0(const int* __restrict__ rowptr, const int* __restrict__ csr0,
                          const float* __restrict__ TT, float* __restrict__ A_) {
  int n = blockIdx.x * 4 + (threadIdx.x >> 6);
  int lane = threadIdx.x & 63;
  int beg = rowptr[n], end = rowptr[n + 1];
  float ax = 0.f, ay = 0.f;
  int i = beg;
  int alim = (beg + 3) & ~3;
  for (; i < end && i < alim; i++) {
    float2 v = *(const float2*)&TT[csr0[i] * 128 + lane * 2];
    ax += v.x; ay += v.y;
  }
  for (; i + 7 < end; i += 8) {
    int4 c0 = *(const int4*)&csr0[i];
    int4 c1 = *(const int4*)&csr0[i + 4];
    float2 v0 = *(const float2*)&TT[c0.x * 128 + lane * 2];
    float2 v1 = *(const float2*)&TT[c0.y * 128 + lane * 2];
    float2 v2 = *(const float2*)&TT[c0.z * 128 + lane * 2];
    float2 v3 = *(const float2*)&TT[c0.w * 128 + lane * 2];
    float2 v4 = *(const float2*)&TT[c1.x * 128 + lane * 2];
    float2 v5 = *(const float2*)&TT[c1.y * 128 + lane * 2];
    float2 v6 = *(const float2*)&TT[c1.z * 128 + lane * 2];
    float2 v7 = *(const float2*)&TT[c1.w * 128 + lane * 2];
    ax += ((v0.x + v1.x) + (v2.x + v3.x)) + ((v4.x + v5.x) + (v6.x + v7.x));
    ay += ((v0.y + v1.y) + (v2.y + v3.y)) + ((v4.y + v5.y) + (v6.y + v7.y));
  }
  for (; i + 3 < end; i += 4) {
    int4 c0 = *(const int4*)&csr0[i];
    float2 v0 = *(const float2*)&TT[c0.x * 128 + lane * 2];
    float2 v1 = *(const float2*)&TT[c0.y * 128 + lane * 2];
    float2 v2 = *(const float2*)&TT[c0.z * 128 + lane * 2];
    float2 v3 = *(const float2*)&TT[c0.w * 128 + lane * 2];
    ax += (v0.x + v1.x) + (v2.x + v3.x);
    ay += (v0.y + v1.y) + (v2.y + v3.y);
  }
  for (; i < end; i++) {
    float2 v = *(const float2*)&TT[csr0[i] * 128 + lane * 2];
    ax += v.x; ay += v.y;
  }
  float2 o; o.x = ax; o.y = ay;
  *(float2*)&A_[n * 128 + lane * 2] = o;
}

// ---------------------------------------------------------------------------
// Gather messages: A[n] = sum M_bf16[csr[i]]  (256 B rows), same batching.
// ---------------------------------------------------------------------------
__global__ void k_gather(const int* __restrict__ rowptr, const int* __restrict__ csr,
                         const __hip_bfloat16* __restrict__ M, float* __restrict__ A_) {
  int n = blockIdx.x * 4 + (threadIdx.x >> 6);
  int lane = threadIdx.x & 63;
  int beg = rowptr[n], end = rowptr[n + 1];
  float ax = 0.f, ay = 0.f;
  int i = beg;
  int alim = (beg + 3) & ~3;
  for (; i < end && i < alim; i++) {
    float2 v = __bfloat1622float2(*(const __hip_bfloat162*)&M[csr[i] * 128 + lane * 2]);
    ax += v.x; ay += v.y;
  }
  for (; i + 7 < end; i += 8) {
    int4 c0 = *(const int4*)&csr[i];
    int4 c1 = *(const int4*)&csr[i + 4];
    float2 v0 = __bfloat1622float2(*(const __hip_bfloat162*)&M[c0.x * 128 + lane * 2]);
    float2 v1 = __bfloat1622float2(*(const __hip_bfloat162*)&M[c0.y * 128 + lane * 2]);
    float2 v2 = __bfloat1622float2(*(const __hip_bfloat162*)&M[c0.z * 128 + lane * 2]);
    float2 v3 = __bfloat1622float2(*(const __hip_bfloat162*)&M[c0.w * 128 + lane * 2]);
    float2 v4 = __bfloat1622float2(*(const __hip_bfloat162*)&M[c1.x * 128 + lane * 2]);
    float2 v5 = __bfloat1622float2(*(const __hip_bfloat162*)&M[c1.y * 128 + lane * 2]);
    float2 v6 = __bfloat1622float2(*(const __hip_bfloat162*)&M[c1.z * 128 + lane * 2]);
    float2 v7 = __bfloat1622float2(*(const __hip_bfloat162*)&M[c1.w * 128 + lane * 2]);
    ax += ((v0.x + v1.x) + (v2.x + v3.x)) + ((v4.x + v5.x) + (v6.x + v7.x));
    ay += ((v0.y + v1.y) + (v2.y + v3.y)) + ((v4.y + v5.y) + (v6.y + v7.y));
  }
  for (; i + 3 < end; i += 4) {
    int4 c0 = *(const int4*)&csr[i];
    float2 v0 = __bfloat1622float2(*(const __hip_bfloat162*)&M[c0.x * 128 + lane * 2]);
    float2 v1 = __bfloat1622float2(*(const __hip_bfloat162*)&M[c0.y * 128 + lane * 2]);
    float2 v2 = __bfloat1622float2(*(const __hip_bfloat162*)&M[c0.z * 128 + lane * 2]);
    float2 v3 = __bfloat1622float2(*(const __hip_bfloat162*)&M[c0.w * 128 + lane * 2]);
    ax += (v0.x + v1.x) + (v2.x + v3.x);
    ay += (v0.y + v1.y) + (v2.y + v3.y);
  }
  for (; i < end; i++) {
    float2 v = __bfloat1622float2(*(const __hip_bfloat162*)&M[csr[i] * 128 + lane * 2]);
    ax += v.x; ay += v.y;
  }
  float2 o; o.x = ax; o.y = ay;
  *(float2*)&A_[n * 128 + lane * 2] = o;
}

// ---------------------------------------------------------------------------
// k_mm1: B = A @ Wu1[192:320,:]  fp32 tiled GEMM.
// ---------------------------------------------------------------------------
__global__ __launch_bounds__(256, 4) void k_mm1(const float* __restrict__ A_,
                                                const float* __restrict__ Wu1,
                                                float* __restrict__ B_) {
  __shared__ float Hs[64][132];
  int t = threadIdx.x;
  int base = blockIdx.x * 64;
#pragma unroll
  for (int j = 0; j < 8; j++) {
    int idx = j * 256 + t;
    int rr = idx >> 5;
    int kq = idx & 31;
    int n = base + rr;
    if (n >= N_NODES) n = N_NODES - 1;
    float4 v = *(const float4*)&A_[n * 128 + kq * 4];
    *(float4*)&Hs[rr][kq * 4] = v;
  }
  __syncthreads();
  int r0 = (t >> 4) * 4;
  int c0 = (t & 15) * 8;
  const float* W = Wu1 + 192 * 128;
  float acc[4][8];
#pragma unroll
  for (int r = 0; r < 4; r++)
#pragma unroll
    for (int j = 0; j < 8; j++) acc[r][j] = 0.f;
#pragma unroll 2
  for (int kq = 0; kq < 32; kq++) {
    const int k = kq * 4;
    float h0[4], h1[4], h2[4], h3[4];
    *(float4*)h0 = *(const float4*)&Hs[r0][k];
    *(float4*)h1 = *(const float4*)&Hs[r0 + 1][k];
    *(float4*)h2 = *(const float4*)&Hs[r0 + 2][k];
    *(float4*)h3 = *(const float4*)&Hs[r0 + 3][k];
#pragma unroll
    for (int i = 0; i < 4; i++) {
      float w[8];
      *(float4*)&w[0] = *(const float4*)&W[(k + i) * 128 + c0];
      *(float4*)&w[4] = *(const float4*)&W[(k + i) * 128 + c0 + 4];
      float hv[4] = {h0[i], h1[i], h2[i], h3[i]};
#pragma unroll
      for (int r = 0; r < 4; r++)
#pragma unroll
        for (int j = 0; j < 8; j++) acc[r][j] += hv[r] * w[j];
    }
  }
#pragma unroll
  for (int r = 0; r < 4; r++) {
    int n = base + r0 + r;
    if (n < N_NODES) {
      float4 o0, o1;
      o0.x = acc[r][0]; o0.y = acc[r][1]; o0.z = acc[r][2]; o0.w = acc[r][3];
      o1.x = acc[r][4]; o1.y = acc[r][5]; o1.z = acc[r][6]; o1.w = acc[r][7];
      *(float4*)&B_[n * 128 + c0] = o0;
      *(float4*)&B_[n * 128 + c0 + 4] = o1;
    }
  }
}

// ---------------------------------------------------------------------------
// k_mm2 v4 (wave-pair MFMA) — unchanged from round 8.
// ---------------------------------------------------------------------------
__global__ __launch_bounds__(256, 2) void k_mm2(const float* __restrict__ B_,
                                                const int* __restrict__ x,
                                                const float* __restrict__ U1,
                                                const float* __restrict__ U2c,
                                                const short* __restrict__ Wt,
                                                const short* __restrict__ Wlo,
                                                const float* __restrict__ bu2,
                                                __hip_bfloat16* __restrict__ M) {
  __shared__ short mbuf[2][16][132];
  int t = threadIdx.x;
  int lane = t & 63;
  int m = lane & 15;
  int quad = lane >> 4;
  int wid = t >> 6;
  int pairid = wid >> 1;
  int h = wid & 1;

  short8 whi[4][4], wlo[4][4];
#pragma unroll
  for (int kc = 0; kc < 4; kc++)
#pragma unroll
    for (int nt = 0; nt < 4; nt++) {
      int n = h * 64 + nt * 16 + m;
      whi[kc][nt] = *(const short8*)&Wt[n * 128 + kc * 32 + quad * 8];
      wlo[kc][nt] = *(const short8*)&Wlo[n * 128 + kc * 32 + quad * 8];
    }
  float bias[4];
#pragma unroll
  for (int nt = 0; nt < 4; nt++) bias[nt] = bu2[h * 64 + nt * 16 + m];

  for (int iter = 0; iter < 7; iter++) {
    int s = iter * 2048 + blockIdx.x * 2 + pairid;
    if (s < 12500) {
      int node = s * 4 + (m >> 2);
      int attr = m & 3;
      int xn = x[node];
      f32x4 acc[4];
#pragma unroll
      for (int nt = 0; nt < 4; nt++) acc[nt] = (f32x4){0.f, 0.f, 0.f, 0.f};

#pragma unroll
      for (int kc = 0; kc < 4; kc++) {
        int k0 = kc * 32 + quad * 8;
        short8 ahi, alo;
        {
          float u1a[8], bba[8], u2a[8];
          *(float4*)&u1a[0] = *(const float4*)&U1[xn * 128 + k0];
          *(float4*)&u1a[4] = *(const float4*)&U1[xn * 128 + k0 + 4];
          *(float4*)&bba[0] = *(const float4*)&B_[node * 128 + k0];
          *(float4*)&bba[4] = *(const float4*)&B_[node * 128 + k0 + 4];
          *(float4*)&u2a[0] = *(const float4*)&U2c[attr * 128 + k0];
          *(float4*)&u2a[4] = *(const float4*)&U2c[attr * 128 + k0 + 4];
#pragma unroll
          for (int j = 0; j < 8; j++) {
            float hv = u1a[j] + bba[j] + u2a[j];
            hv = hv > 0.f ? hv : 0.f;
            bfbits hi; hi.b = __float2bfloat16(hv);
            float hf = __bfloat162float(hi.b);
            bfbits lo; lo.b = __float2bfloat16(hv - hf);
            ahi[j] = hi.s;
            alo[j] = lo.s;
          }
        }
#pragma unroll
        for (int nt = 0; nt < 4; nt++) {
          acc[nt] = __builtin_amdgcn_mfma_f32_16x16x32_bf16(ahi, whi[kc][nt], acc[nt], 0, 0, 0);
          acc[nt] = __builtin_amdgcn_mfma_f32_16x16x32_bf16(alo, whi[kc][nt], acc[nt], 0, 0, 0);
          acc[nt] = __builtin_amdgcn_mfma_f32_16x16x32_bf16(ahi, wlo[kc][nt], acc[nt], 0, 0, 0);
        }
      }

#pragma unroll
      for (int nt = 0; nt < 4; nt++) {
#pragma unroll
        for (int r = 0; r < 4; r++) {
          float v = acc[nt][r] + bias[nt];
          v = v > 0.f ? v : 0.f;
          bfbits o; o.b = __float2bfloat16(v);
          mbuf[pairid][quad * 4 + r][h * 64 + nt * 16 + m] = o.s;
        }
      }
    }
    __syncthreads();
#pragma unroll
    for (int p = 0; p < 2; p++) {
      int chunk = p * 256 + t;
      int row = chunk >> 4;
      int sg = iter * 2048 + blockIdx.x * 2 + (row >> 4);
      if (sg < 12500) {
        int r = row & 15;
        short8 v = *(const short8*)&mbuf[row >> 4][r][(chunk & 15) * 8];
        *(short8*)((short*)M + (sg * 16 + r) * 128 + (chunk & 15) * 8) = v;
      }
    }
    __syncthreads();
  }
}

// ---------------------------------------------------------------------------
// mol[m] = sum of A rows in [molptr[m], molptr[m+1]) — one wave per mol.
// ---------------------------------------------------------------------------
__global__ void k_molgather(const float* __restrict__ A_, const int* __restrict__ molptr,
                            float* __restrict__ mol) {
  int m = blockIdx.x * 4 + (threadIdx.x >> 6);
  int lane = threadIdx.x & 63;
  int beg = molptr[m], end = molptr[m + 1];
  float ax = 0.f, ay = 0.f;
  int n = beg;
  for (; n + 1 < end; n += 2) {
    float2 v0 = *(const float2*)&A_[n * 128 + lane * 2];
    float2 v1 = *(const float2*)&A_[(n + 1) * 128 + lane * 2];
    ax += v0.x + v1.x;
    ay += v0.y + v1.y;
  }
  if (n < end) {
    float2 v0 = *(const float2*)&A_[n * 128 + lane * 2];
    ax += v0.x;
    ay += v0.y;
  }
  float2 o; o.x = ax; o.y = ay;
  *(float2*)&mol[m * 128 + lane * 2] = o;
}

// ---------------------------------------------------------------------------
// out[m] = relu(mol[m] @ Wr1 + br1) @ Wr2 + br2
// ---------------------------------------------------------------------------
__global__ __launch_bounds__(256) void k_readout(const float* __restrict__ mol,
                                                 const float* __restrict__ Wr1,
                                                 const float* __restrict__ br1,
                                                 const float* __restrict__ Wr2,
                                                 const float* __restrict__ br2,
                                                 float* __restrict__ out) {
  int m = blockIdx.x;
  __shared__ float ms[128];
  __shared__ float red[256];
  int t = threadIdx.x;
  if (t < 128) ms[t] = mol[m * 128 + t];
  __syncthreads();
  float part = 0.f;
#pragma unroll
  for (int jj = 0; jj < 2; jj++) {
    int j = t + jj * 256;
    float acc = br1[j];
#pragma unroll
    for (int k = 0; k < 128; k += 4) {
      float4 m4 = *(const float4*)&ms[k];
      acc += m4.x * Wr1[k * 512 + j] + m4.y * Wr1[(k + 1) * 512 + j] +
             m4.z * Wr1[(k + 2) * 512 + j] + m4.w * Wr1[(k + 3) * 512 + j];
    }
    acc = acc > 0.f ? acc : 0.f;
    part += acc * Wr2[j];
  }
  red[t] = part;
  __syncthreads();
  for (int s = 128; s > 0; s >>= 1) {
    if (t < s) red[t] += red[t + s];
    __syncthreads();
  }
  if (t == 0) out[m] = red[0] + br2[0];
}

// ---------------------------------------------------------------------------
extern "C" void kernel_launch(void* const* d_in, const int* in_sizes, int n_in,
                              void* d_out, int out_size, void* d_ws, size_t ws_size,
                              hipStream_t stream) {
  const int* x        = (const int*)d_in[0];
  const int* eattr    = (const int*)d_in[1];
  const int* eidx     = (const int*)d_in[2];
  const int* batch    = (const int*)d_in[3];
  const float* atom_table = (const float*)d_in[4];
  const float* bond_table = (const float*)d_in[5];
  const float* Wi  = (const float*)d_in[6];
  const float* bi  = (const float*)d_in[7];
  const float* Wu1 = (const float*)d_in[8];
  const float* bu1 = (const float*)d_in[9];
  const float* Wu2 = (const float*)d_in[10];
  const float* bu2 = (const float*)d_in[11];
  const float* Wr1 = (const float*)d_in[12];
  const float* br1 = (const float*)d_in[13];
  const float* Wr2 = (const float*)d_in[14];
  const float* br2 = (const float*)d_in[15];
  float* out = (float*)d_out;

  char* ws = (char*)d_ws;
  __hip_bfloat16* M = (__hip_bfloat16*)(ws);       //  51,200,000 B (bf16)
  short* Wt      = (short*)(ws + 51200000);        //      32,768 B
  short* Wlo     = (short*)(ws + 51232768);        //      32,768 B
  int*   csr0    = (int*)  (ws + 51265536);        //   3,200,000 B (type-row idx)
  int*   locinc  = (int*)  (ws + 54465536);        //     200,000 B
  int*   partial = (int*)  (ws + 54665536);        //         256 B
  int*   offs    = (int*)  (ws + 54665792);        //         256 B
  int*   molptr  = (int*)  (ws + 54666048);        //       8,004 B
  float* A       = (float*)(ws + 102400000);       //  25,600,000 B
  float* B       = (float*)(ws + 128000000);       //  25,600,000 B
  int*   csr     = (int*)  (ws + 153600000);       //   3,200,000 B
  int*   rowptr  = (int*)  (ws + 156800000);       //     200,064 B
  float* T1      = (float*)(ws + 157000064);       //      60,928 B
  float* U1      = (float*)(ws + 157060992);       //      60,928 B
  float* T2c     = (float*)(ws + 157121920);       //       2,048 B
  float* U2c     = (float*)(ws + 157123968);       //       2,048 B
  float* TT      = (float*)(ws + 157126016);       //     243,712 B
  float* mol     = (float*)(ws + 157369728);       //   1,024,000 B
  // cnt/cursor alias B: only live before the first k_mm1 write to B.
  int*   cnt     = (int*)B;
  int*   cursor  = (int*)(ws + 128000000 + 204800);

  hipMemsetAsync(cnt, 0, N_NODES * sizeof(int), stream);
  k_tables<<<123, 128, 0, stream>>>(atom_table, bond_table, Wi, bi, Wu1, bu1,
                                    T1, U1, T2c, U2c);
  k_tt<<<476, 128, 0, stream>>>(T1, T2c, TT);
  k_wt<<<128, 128, 0, stream>>>(Wu2, Wt, Wlo);
  k_hist<<<N_EDGES / 256, 256, 0, stream>>>(eidx, cnt);
  k_scanA<<<49, 1024, 0, stream>>>(cnt, locinc, partial);
  k_scanB<<<1, 64, 0, stream>>>(partial, offs);
  k_scanC<<<(N_NODES + 255) / 256, 256, 0, stream>>>(cnt, locinc, offs, rowptr, cursor);
  k_fill<<<N_EDGES / 256, 256, 0, stream>>>(eidx, eattr, x, cursor, csr, csr0);
  k_molptr<<<(NUM_MOL + 256) / 256, 256, 0, stream>>>(batch, molptr);

  k_gather0<<<N_NODES / 4, 256, 0, stream>>>(rowptr, csr0, TT, A);

  for (int p = 0; p < 4; p++) {
    k_mm1<<<(N_NODES + 63) / 64, 256, 0, stream>>>(A, Wu1, B);
    k_mm2<<<1024, 256, 0, stream>>>(B, x, U1, U2c, Wt, Wlo, bu2, M);
    k_gather<<<N_NODES / 4, 256, 0, stream>>>(rowptr, csr, M, A);
  }

  k_molgather<<<NUM_MOL / 4, 256, 0, stream>>>(A, molptr, mol);
  k_readout<<<NUM_MOL, 256, 0, stream>>>(mol, Wr1, br1, Wr2, br2, out);
}